// Round 1
// baseline (155.775 us; speedup 1.0000x reference)
//
#include <hip/hip_runtime.h>
#include <math.h>

// WfcNN: B=262144.
//   h1 = tanh(x @ W0 + b0)            (B,128)
//   h2 = tanh(h1 @ W1 + b1)           (B,64)
//   g  = tanh(h2 . Wa[eid] + ba[eid]) (B,32)
//   psi= g . Wb[eid] + bb[eid]        (B,2) ; out = psi / sqrt(|psi|^2+1e-6)
//
// Round 10: attack latency, not ALU.
//  - Prologue (was ~60us of the 142): HB 128->1024 (8x grid parallelism for
//    hist+scatter; 1 item/thread; LDS-atomic contention hidden by TLP).
//  - wfc: 256-thread/256-sample blocks -> 64-thread/64-sample blocks.
//    Per-wave instruction stream is UNCHANGED (each wave always owned its own
//    64 rows); LDS/block 36864->9216 B => ~16 blocks/CU resident (was 3),
//    1-wave barriers are ~free, 4x finer scheduling tail.
//  - Per-block (eid,start,cnt) descriptors precomputed in a spare scatter
//    block (int4 load) -- the 30-iter serial etot scan would not amortize
//    over 4126 small blocks.
// Numerics bit-identical to R9 (same staging math, same 3-pass split-bf16
// MFMA). Cooperative fusion FAILED in R8 -- do not retry.

#define THREADS 64
#define NE 30
#define HB 1024
#define MAXBLK 4126       // 262144/64 + 30 partial blocks
#define SA 67             // u32 row stride for [k][sample] staging (64+3)
#define SG 36             // f32 row stride for [sample][h] g staging

typedef short bf16x8 __attribute__((ext_vector_type(8)));
typedef float f32x4 __attribute__((ext_vector_type(4)));

__device__ __forceinline__ int expert_id(int nn, int ll, int mm) {
    return ((nn - 1) * nn * (2 * nn - 1)) / 6 + ll * ll + ll + mm;
}

// tanh(v) = 1 - 2/(exp2(2*log2e*v)+1); saturates correctly, no clamp.
__device__ __forceinline__ float fast_tanh(float v) {
    float e = __builtin_exp2f(v * 2.885390082f);
    return fmaf(-2.0f, __builtin_amdgcn_rcpf(e + 1.0f), 1.0f);
}

__device__ __forceinline__ unsigned int f2b(float f) {   // f32 -> bf16 RNE
    unsigned int u = __float_as_uint(f);
    return (u + 0x7fffu + ((u >> 16) & 1u)) >> 16;
}
__device__ __forceinline__ float b2f(unsigned int b) {
    return __uint_as_float(b << 16);
}
// runtime split: RNE hi, truncated lo; packed (lo16<<16)|hi16
__device__ __forceinline__ unsigned int packsplit(float v) {
    const unsigned int hb = f2b(v);
    const float lo = v - b2f(hb);
    return (__float_as_uint(lo) & 0xffff0000u) | hb;
}

union U8 { unsigned int u[4]; bf16x8 v; };
// packed words -> hi-plane / lo-plane bf16x8 (bit-identical to shift/mask form)
__device__ __forceinline__ void unpack8(const unsigned int* w, bf16x8& hi, bf16x8& lo) {
    U8 H, L;
#pragma unroll
    for (int i = 0; i < 4; ++i) {
        H.u[i] = __builtin_amdgcn_perm(w[2 * i + 1], w[2 * i], 0x05040100u);
        L.u[i] = __builtin_amdgcn_perm(w[2 * i + 1], w[2 * i], 0x07060302u);
    }
    hi = H.v; lo = L.v;
}

// ---- K1: hist + eid cache + bucket base reservation + weight splitting ----
__global__ void hist_pack_kernel(const int* __restrict__ nq, const int* __restrict__ lq,
                                 const int* __restrict__ mq,
                                 int* __restrict__ eids, int* __restrict__ etot,
                                 int* __restrict__ bbase,
                                 const float* __restrict__ W1,
                                 unsigned short* __restrict__ W1fh, unsigned short* __restrict__ W1fl,
                                 const float* __restrict__ Wa,
                                 unsigned short* __restrict__ Wafh, unsigned short* __restrict__ Wafl,
                                 int B) {
    const int tid = threadIdx.x;
    const int bx = blockIdx.x;
    if (bx < HB) {
        __shared__ int h[NE];
        if (tid < NE) h[tid] = 0;
        __syncthreads();
        const int per = B / HB, base = bx * per;
        for (int i = tid; i < per; i += blockDim.x) {
            const int e = expert_id(nq[base + i], lq[base + i], mq[base + i]);
            eids[base + i] = e;
            atomicAdd(&h[e], 1);
        }
        __syncthreads();
        if (tid < NE) bbase[bx * NE + tid] = atomicAdd(&etot[tid], h[tid]);
    } else if (bx == HB) {
        // W1 (128,64) -> hi/lo planes in B-frag order (rec=((c*4+nt)*4+qd)*16+l16)
        for (int i = tid; i < 8192; i += blockDim.x) {
            const int j = i & 7, s = (i >> 3) & 15, q = (i >> 7) & 3;
            const int nt = (i >> 9) & 3, c = i >> 11;
            const int k = c * 32 + q * 8 + j, n = nt * 16 + s;
            const float w = W1[k * 64 + n];
            const unsigned int hb = f2b(w);
            W1fh[i] = (unsigned short)hb;
            W1fl[i] = (unsigned short)f2b(w - b2f(hb));
        }
    } else {
        // Wa[e] (64,32) -> hi/lo planes (rec=((c2*2+nt2)*4+qd)*16+l16)
        const int e = bx - HB - 1;
        for (int i = tid; i < 2048; i += blockDim.x) {
            const int j = i & 7, s = (i >> 3) & 15, q = (i >> 7) & 3;
            const int nt2 = (i >> 9) & 1, c2 = (i >> 10) & 1;
            const int d = c2 * 32 + q * 8 + j, hh = nt2 * 16 + s;
            const float w = Wa[e * 2048 + d * 32 + hh];
            const unsigned int hb = f2b(w);
            Wafh[e * 2048 + i] = (unsigned short)hb;
            Wafl[e * 2048 + i] = (unsigned short)f2b(w - b2f(hb));
        }
    }
}

// ---- K2: scatter into sorted order + per-block descriptor build ----
__global__ void scatter_kernel(const int* __restrict__ eids, const int* __restrict__ etot,
                               const int* __restrict__ bbase, int* __restrict__ perm,
                               int4* __restrict__ desc, int B) {
    const int tid = threadIdx.x;
    if (blockIdx.x == HB) {
        // build (eid, start, cnt) for every wfc block; -1 pads the fixed grid
        __shared__ int es[NE], tq[NE], pb[NE + 1];
        if (tid == 0) {
            int e0 = 0, c = 0;
            for (int e = 0; e < NE; ++e) {
                const int t = etot[e];
                es[e] = e0; tq[e] = t; pb[e] = c;
                c += (t + THREADS - 1) >> 6;
                e0 += t;
            }
            pb[NE] = c;
        }
        __syncthreads();
        const int tot = pb[NE];
        for (int b = tid; b < MAXBLK; b += blockDim.x) {
            int4 d = make_int4(-1, 0, 0, 0);
            if (b < tot) {
                int e = 0;
                while (pb[e + 1] <= b) ++e;
                const int seg = b - pb[e];
                d.x = e;
                d.y = es[e] + (seg << 6);
                d.z = min(THREADS, tq[e] - (seg << 6));
            }
            desc[b] = d;
        }
        return;
    }
    __shared__ int lcnt[NE], esrt[NE], bb[NE];
    if (tid < NE) { lcnt[tid] = 0; bb[tid] = bbase[blockIdx.x * NE + tid]; }
    if (tid == 0) {
        int es0 = 0;
        for (int e = 0; e < NE; ++e) { esrt[e] = es0; es0 += etot[e]; }
    }
    __syncthreads();
    const int per = B / HB;
    const int blk = blockIdx.x * per;
    for (int i = tid; i < per; i += blockDim.x) {
        const int idx = blk + i;
        const int e = eids[idx];
        const int r = atomicAdd(&lcnt[e], 1);
        perm[esrt[e] + bb[e] + r] = idx;
    }
}

// ---- K3: fused MLP; layer2 + expert-A on MFMA (3-pass split-bf16) ----
// 64 threads = 1 wave = 64 samples; LDS 9216B => ~16 blocks/CU resident.
__global__ __launch_bounds__(THREADS, 4) void wfc_kernel(
    const float* __restrict__ x, const int* __restrict__ perm,
    const int4* __restrict__ desc,
    const float* __restrict__ W0, const float* __restrict__ b0,
    const bf16x8* __restrict__ W1fh, const bf16x8* __restrict__ W1fl,
    const float* __restrict__ b1,
    const bf16x8* __restrict__ Wafh, const bf16x8* __restrict__ Wafl,
    const float* __restrict__ ba,
    const float* __restrict__ Wb, const float* __restrict__ bb,
    float* __restrict__ out)
{
    __shared__ unsigned int sbuf[2304];      // max(32*SA, 64*SG) u32 = 9216 B

    const int4 dsc = desc[blockIdx.x];
    if (dsc.x < 0) return;
    const int eid  = __builtin_amdgcn_readfirstlane(dsc.x);
    const int start = dsc.y;
    const int cnt   = dsc.z;

    const int tid = threadIdx.x;
    const bool valid = tid < cnt;
    const int idx = perm[start + (valid ? tid : 0)];

    const int lane = tid & 63;
    const int wv   = tid >> 6;               // always 0 (1 wave); kept generic
    const int qd   = lane >> 4;
    const int l16  = lane & 15;

    const float x0 = x[idx * 3 + 0];
    const float x1 = x[idx * 3 + 1];
    const float x2 = x[idx * 3 + 2];

    // ---- layer 2 accumulators, init b1 (C layout: col = l16) ----
    f32x4 acc[4][4];
#pragma unroll
    for (int nt = 0; nt < 4; ++nt) {
        const float bv = b1[nt * 16 + l16];
#pragma unroll
        for (int mt = 0; mt < 4; ++mt) {
            f32x4 c; c[0] = bv; c[1] = bv; c[2] = bv; c[3] = bv;
            acc[mt][nt] = c;
        }
    }

    // ---- layer-2 GEMM: 4 K-chunks of 32 ----
    for (int c = 0; c < 4; ++c) {
        if (c) __syncthreads();
#pragma unroll
        for (int kk = 0; kk < 32; ++kk) {
            const int k = c * 32 + kk;
            const float pre = fmaf(x0, W0[k], fmaf(x1, W0[128 + k], fmaf(x2, W0[256 + k], b0[k])));
            sbuf[kk * SA + tid] = packsplit(fast_tanh(pre));
        }
        __syncthreads();

        bf16x8 Bhi[4], Blo[4];
#pragma unroll
        for (int nt = 0; nt < 4; ++nt) {
            const int rec = (c * 4 + nt) * 64 + qd * 16 + l16;
            Bhi[nt] = W1fh[rec];
            Blo[nt] = W1fl[rec];
        }
#pragma unroll
        for (int mt = 0; mt < 4; ++mt) {
            unsigned int a[8];
            const int mrow = wv * 64 + mt * 16 + l16;
#pragma unroll
            for (int j = 0; j < 8; ++j) a[j] = sbuf[(qd * 8 + j) * SA + mrow];
            bf16x8 Ahi, Alo;
            unpack8(a, Ahi, Alo);
#pragma unroll
            for (int nt = 0; nt < 4; ++nt) {
                acc[mt][nt] = __builtin_amdgcn_mfma_f32_16x16x32_bf16(Ahi, Bhi[nt], acc[mt][nt], 0, 0, 0);
                acc[mt][nt] = __builtin_amdgcn_mfma_f32_16x16x32_bf16(Ahi, Blo[nt], acc[mt][nt], 0, 0, 0);
                acc[mt][nt] = __builtin_amdgcn_mfma_f32_16x16x32_bf16(Alo, Bhi[nt], acc[mt][nt], 0, 0, 0);
            }
        }
    }

    // ---- expert-A accumulators, init ba ----
    f32x4 acc2[4][2];
#pragma unroll
    for (int nt2 = 0; nt2 < 2; ++nt2) {
        const float bv = ba[(eid << 5) + nt2 * 16 + l16];
#pragma unroll
        for (int mt = 0; mt < 4; ++mt) {
            f32x4 c; c[0] = bv; c[1] = bv; c[2] = bv; c[3] = bv;
            acc2[mt][nt2] = c;
        }
    }

    // ---- expert-A GEMM: h2 = tanh(acc) restaged [d][sample]; 2 K-chunks ----
    const bf16x8* __restrict__ waeh = Wafh + (eid << 8);
    const bf16x8* __restrict__ wael = Wafl + (eid << 8);
    for (int c2 = 0; c2 < 2; ++c2) {
        __syncthreads();
#pragma unroll
        for (int mt = 0; mt < 4; ++mt) {
#pragma unroll
            for (int ntl = 0; ntl < 2; ++ntl) {
#pragma unroll
                for (int r = 0; r < 4; ++r) {
                    const float h2 = fast_tanh(acc[mt][c2 * 2 + ntl][r]);
                    const int dl  = ntl * 16 + l16;
                    const int row = wv * 64 + mt * 16 + qd * 4 + r;
                    sbuf[dl * SA + row] = packsplit(h2);
                }
            }
        }
        __syncthreads();

        bf16x8 B2hi[2], B2lo[2];
#pragma unroll
        for (int nt2 = 0; nt2 < 2; ++nt2) {
            const int rec = (c2 * 2 + nt2) * 64 + qd * 16 + l16;
            B2hi[nt2] = waeh[rec];
            B2lo[nt2] = wael[rec];
        }
#pragma unroll
        for (int mt = 0; mt < 4; ++mt) {
            unsigned int a[8];
            const int mrow = wv * 64 + mt * 16 + l16;
#pragma unroll
            for (int j = 0; j < 8; ++j) a[j] = sbuf[(qd * 8 + j) * SA + mrow];
            bf16x8 Ahi, Alo;
            unpack8(a, Ahi, Alo);
#pragma unroll
            for (int nt2 = 0; nt2 < 2; ++nt2) {
                acc2[mt][nt2] = __builtin_amdgcn_mfma_f32_16x16x32_bf16(Ahi, B2hi[nt2], acc2[mt][nt2], 0, 0, 0);
                acc2[mt][nt2] = __builtin_amdgcn_mfma_f32_16x16x32_bf16(Ahi, B2lo[nt2], acc2[mt][nt2], 0, 0, 0);
                acc2[mt][nt2] = __builtin_amdgcn_mfma_f32_16x16x32_bf16(Alo, B2hi[nt2], acc2[mt][nt2], 0, 0, 0);
            }
        }
    }

    // ---- g = tanh(acc2) staged [sample][h], expert-B per-thread ----
    __syncthreads();
    float* g2 = (float*)sbuf;
#pragma unroll
    for (int mt = 0; mt < 4; ++mt) {
#pragma unroll
        for (int nt2 = 0; nt2 < 2; ++nt2) {
#pragma unroll
            for (int r = 0; r < 4; ++r) {
                const int row = wv * 64 + mt * 16 + qd * 4 + r;
                g2[row * SG + nt2 * 16 + l16] = fast_tanh(acc2[mt][nt2][r]);
            }
        }
    }
    __syncthreads();

    float gv[32];
    {
        const float4* grow = (const float4*)(g2 + tid * SG);
#pragma unroll
        for (int i = 0; i < 8; ++i) {
            float4 v = grow[i];
            gv[4 * i + 0] = v.x; gv[4 * i + 1] = v.y;
            gv[4 * i + 2] = v.z; gv[4 * i + 3] = v.w;
        }
    }

    const float* __restrict__ wbe = Wb + (eid << 6);
    float p0 = bb[2 * eid], p1 = bb[2 * eid + 1];
#pragma unroll
    for (int h = 0; h < 32; ++h) {
        p0 = fmaf(gv[h], wbe[2 * h + 0], p0);
        p1 = fmaf(gv[h], wbe[2 * h + 1], p1);
    }

    const float s = fmaf(p0, p0, fmaf(p1, p1, 1e-6f));
    const float inv = 1.0f / sqrtf(s);
    if (valid) {
        float2 o; o.x = p0 * inv; o.y = p1 * inv;
        ((float2*)out)[idx] = o;
    }
}

extern "C" void kernel_launch(void* const* d_in, const int* in_sizes, int n_in,
                              void* d_out, int out_size, void* d_ws, size_t ws_size,
                              hipStream_t stream) {
    const float* x  = (const float*)d_in[0];
    const int*   n  = (const int*)d_in[1];
    const int*   l  = (const int*)d_in[2];
    const int*   m  = (const int*)d_in[3];
    const float* W0 = (const float*)d_in[4];
    const float* b0 = (const float*)d_in[5];
    const float* W1 = (const float*)d_in[6];
    const float* b1 = (const float*)d_in[7];
    const float* Wa = (const float*)d_in[8];
    const float* ba = (const float*)d_in[9];
    const float* Wb = (const float*)d_in[10];
    const float* bb = (const float*)d_in[11];
    float* out = (float*)d_out;

    const int B = in_sizes[1];   // 262144

    // workspace layout (all segments 16B aligned)
    int*            perm  = (int*)d_ws;                      // B
    int*            eids  = perm + B;                        // B
    int*            bbase = eids + B;                        // HB*NE = 30720
    int*            etot  = bbase + HB * NE;                 // 32
    int4*           desc  = (int4*)(etot + 32);              // MAXBLK int4
    unsigned short* W1fh  = (unsigned short*)(desc + MAXBLK);// 8192 u16
    unsigned short* W1fl  = W1fh + 8192;                     // 8192 u16
    unsigned short* Wafh  = W1fl + 8192;                     // 30*2048 u16
    unsigned short* Wafl  = Wafh + NE * 2048;                // 30*2048 u16

    hipMemsetAsync(etot, 0, 32 * sizeof(int), stream);
    hist_pack_kernel<<<HB + 1 + NE, 256, 0, stream>>>(
        n, l, m, eids, etot, bbase, W1, W1fh, W1fl, Wa, Wafh, Wafl, B);
    scatter_kernel<<<HB + 1, 256, 0, stream>>>(eids, etot, bbase, perm, desc, B);
    wfc_kernel<<<MAXBLK, THREADS, 0, stream>>>(
        x, perm, desc, W0, b0,
        (const bf16x8*)W1fh, (const bf16x8*)W1fl, b1,
        (const bf16x8*)Wafh, (const bf16x8*)Wafl, ba, Wb, bb, out);
}

// Round 4
// 147.017 us; speedup vs baseline: 1.0596x; 1.0596x over previous
//
#include <hip/hip_runtime.h>
#include <math.h>

// WfcNN: B=262144.
//   h1 = tanh(x @ W0 + b0)            (B,128)
//   h2 = tanh(h1 @ W1 + b1)           (B,64)
//   g  = tanh(h2 . Wa[eid] + ba[eid]) (B,32)
//   psi= g . Wb[eid] + bb[eid]        (B,2) ; out = psi / sqrt(|psi|^2+1e-6)
//
// Round 13: hedge after two container failures on the counting-sort rewrite
// (no kernel verdict either time). Keep the R10/R1-proven kernel SHAPES
// (global-atomic reservation + LDS-atomic scatter + desc side-block) and fix
// the two diagnosed prologue costs with a minimal diff:
//  - etot padded to ONE COUNTER PER 64B LINE (etot[e*16]): the R10 prologue
//    regression theory was 30720 atomicAdds serializing on 2 cache lines.
//    Now <=256 ops/line, 30 lines in parallel.
//  - HB 1024->256: 4x fewer reservation atomics; perm run length 8.5->~34
//    restores wfc x-gather/out-write locality.
//  - serial global etot scans -> shared preload (30 threads) + LDS scan.
// wfc_kernel BIT-IDENTICAL to R10/R11 (56.5us measured at run-length 8.5).
// Cooperative fusion FAILED in R8 -- do not retry.

#define THREADS 64        // wfc block = 1 wave = 64 samples
#define NE 30
#define HB 256            // hist/scatter blocks; PER = B/HB = 1024
#define PER 1024
#define ETS 16            // etot stride in ints: one counter per 64B line
#define MAXBLK 4126       // 262144/64 + 30 partial blocks
#define SA 67             // u32 row stride for [k][sample] staging (64+3)
#define SG 36             // f32 row stride for [sample][h] g staging

typedef short bf16x8 __attribute__((ext_vector_type(8)));
typedef float f32x4 __attribute__((ext_vector_type(4)));

__device__ __forceinline__ int expert_id(int nn, int ll, int mm) {
    return ((nn - 1) * nn * (2 * nn - 1)) / 6 + ll * ll + ll + mm;
}

// tanh(v) = 1 - 2/(exp2(2*log2e*v)+1); saturates correctly, no clamp.
__device__ __forceinline__ float fast_tanh(float v) {
    float e = __builtin_exp2f(v * 2.885390082f);
    return fmaf(-2.0f, __builtin_amdgcn_rcpf(e + 1.0f), 1.0f);
}

__device__ __forceinline__ unsigned int f2b(float f) {   // f32 -> bf16 RNE
    unsigned int u = __float_as_uint(f);
    return (u + 0x7fffu + ((u >> 16) & 1u)) >> 16;
}
__device__ __forceinline__ float b2f(unsigned int b) {
    return __uint_as_float(b << 16);
}
// runtime split: RNE hi, truncated lo; packed (lo16<<16)|hi16
__device__ __forceinline__ unsigned int packsplit(float v) {
    const unsigned int hb = f2b(v);
    const float lo = v - b2f(hb);
    return (__float_as_uint(lo) & 0xffff0000u) | hb;
}

union U8 { unsigned int u[4]; bf16x8 v; };
// packed words -> hi-plane / lo-plane bf16x8 (bit-identical to shift/mask form)
__device__ __forceinline__ void unpack8(const unsigned int* w, bf16x8& hi, bf16x8& lo) {
    U8 H, L;
#pragma unroll
    for (int i = 0; i < 4; ++i) {
        H.u[i] = __builtin_amdgcn_perm(w[2 * i + 1], w[2 * i], 0x05040100u);
        L.u[i] = __builtin_amdgcn_perm(w[2 * i + 1], w[2 * i], 0x07060302u);
    }
    hi = H.v; lo = L.v;
}

// ---- K1: hist + eid cache + bucket base reservation + weight splitting ----
__global__ void hist_pack_kernel(const int* __restrict__ nq, const int* __restrict__ lq,
                                 const int* __restrict__ mq,
                                 int* __restrict__ eids, int* __restrict__ etot,
                                 int* __restrict__ bbase,
                                 const float* __restrict__ W1,
                                 unsigned short* __restrict__ W1fh, unsigned short* __restrict__ W1fl,
                                 const float* __restrict__ Wa,
                                 unsigned short* __restrict__ Wafh, unsigned short* __restrict__ Wafl,
                                 int B) {
    const int tid = threadIdx.x;
    const int bx = blockIdx.x;
    if (bx < HB) {
        __shared__ int h[NE];
        if (tid < NE) h[tid] = 0;
        __syncthreads();
        const int base = bx * PER;
        for (int i = tid; i < PER; i += blockDim.x) {
            const int e = expert_id(nq[base + i], lq[base + i], mq[base + i]);
            eids[base + i] = e;
            atomicAdd(&h[e], 1);                       // LDS
        }
        __syncthreads();
        if (tid < NE)                                  // one 64B line per expert
            bbase[bx * NE + tid] = atomicAdd(&etot[tid * ETS], h[tid]);
    } else if (bx == HB) {
        // W1 (128,64) -> hi/lo planes in B-frag order (rec=((c*4+nt)*4+qd)*16+l16)
        for (int i = tid; i < 8192; i += blockDim.x) {
            const int j = i & 7, s = (i >> 3) & 15, q = (i >> 7) & 3;
            const int nt = (i >> 9) & 3, c = i >> 11;
            const int k = c * 32 + q * 8 + j, n = nt * 16 + s;
            const float w = W1[k * 64 + n];
            const unsigned int hb = f2b(w);
            W1fh[i] = (unsigned short)hb;
            W1fl[i] = (unsigned short)f2b(w - b2f(hb));
        }
    } else {
        // Wa[e] (64,32) -> hi/lo planes (rec=((c2*2+nt2)*4+qd)*16+l16)
        const int e = bx - HB - 1;
        for (int i = tid; i < 2048; i += blockDim.x) {
            const int j = i & 7, s = (i >> 3) & 15, q = (i >> 7) & 3;
            const int nt2 = (i >> 9) & 1, c2 = (i >> 10) & 1;
            const int d = c2 * 32 + q * 8 + j, hh = nt2 * 16 + s;
            const float w = Wa[e * 2048 + d * 32 + hh];
            const unsigned int hb = f2b(w);
            Wafh[e * 2048 + i] = (unsigned short)hb;
            Wafl[e * 2048 + i] = (unsigned short)f2b(w - b2f(hb));
        }
    }
}

// ---- K2: scatter into sorted order + per-block descriptor build ----
__global__ void scatter_kernel(const int* __restrict__ eids, const int* __restrict__ etot,
                               const int* __restrict__ bbase, int* __restrict__ perm,
                               int4* __restrict__ desc, int B) {
    const int tid = threadIdx.x;
    if (blockIdx.x == HB) {
        // build (eid, start, cnt) for every wfc block; -1 pads the fixed grid
        __shared__ int tq[NE], es[NE], pb[NE + 1];
        if (tid < NE) tq[tid] = etot[tid * ETS];       // parallel preload
        __syncthreads();
        if (tid == 0) {
            int e0 = 0, c = 0;
            for (int e = 0; e < NE; ++e) {
                es[e] = e0; pb[e] = c;
                c += (tq[e] + THREADS - 1) >> 6;
                e0 += tq[e];
            }
            pb[NE] = c;
        }
        __syncthreads();
        const int tot = pb[NE];
        for (int b = tid; b < MAXBLK; b += blockDim.x) {
            int4 d = make_int4(-1, 0, 0, 0);
            if (b < tot) {
                int e = 0;
                while (pb[e + 1] <= b) ++e;
                const int seg = b - pb[e];
                d.x = e;
                d.y = es[e] + (seg << 6);
                d.z = min(THREADS, tq[e] - (seg << 6));
            }
            desc[b] = d;
        }
        return;
    }
    __shared__ int lcnt[NE], esrt[NE], bb[NE], tq[NE];
    if (tid < NE) {
        lcnt[tid] = 0;
        bb[tid] = bbase[blockIdx.x * NE + tid];
        tq[tid] = etot[tid * ETS];                     // parallel preload
    }
    __syncthreads();
    if (tid == 0) {
        int es0 = 0;
        for (int e = 0; e < NE; ++e) { esrt[e] = es0; es0 += tq[e]; }
    }
    __syncthreads();
    const int blk = blockIdx.x * PER;
    for (int i = tid; i < PER; i += blockDim.x) {
        const int idx = blk + i;
        const int e = eids[idx];
        const int r = atomicAdd(&lcnt[e], 1);          // LDS
        perm[esrt[e] + bb[e] + r] = idx;
    }
}

// ---- K3: fused MLP; layer2 + expert-A on MFMA (3-pass split-bf16) ----
// 64 threads = 1 wave = 64 samples; LDS 9216B. BIT-IDENTICAL to R10/R11.
__global__ __launch_bounds__(THREADS, 4) void wfc_kernel(
    const float* __restrict__ x, const int* __restrict__ perm,
    const int4* __restrict__ desc,
    const float* __restrict__ W0, const float* __restrict__ b0,
    const bf16x8* __restrict__ W1fh, const bf16x8* __restrict__ W1fl,
    const float* __restrict__ b1,
    const bf16x8* __restrict__ Wafh, const bf16x8* __restrict__ Wafl,
    const float* __restrict__ ba,
    const float* __restrict__ Wb, const float* __restrict__ bb,
    float* __restrict__ out)
{
    __shared__ unsigned int sbuf[2304];      // max(32*SA, 64*SG) u32 = 9216 B

    const int4 dsc = desc[blockIdx.x];
    if (dsc.x < 0) return;
    const int eid  = __builtin_amdgcn_readfirstlane(dsc.x);
    const int start = dsc.y;
    const int cnt   = dsc.z;

    const int tid = threadIdx.x;
    const bool valid = tid < cnt;
    const int idx = perm[start + (valid ? tid : 0)];

    const int lane = tid & 63;
    const int wv   = tid >> 6;               // always 0 (1 wave); kept generic
    const int qd   = lane >> 4;
    const int l16  = lane & 15;

    const float x0 = x[idx * 3 + 0];
    const float x1 = x[idx * 3 + 1];
    const float x2 = x[idx * 3 + 2];

    // ---- layer 2 accumulators, init b1 (C layout: col = l16) ----
    f32x4 acc[4][4];
#pragma unroll
    for (int nt = 0; nt < 4; ++nt) {
        const float bv = b1[nt * 16 + l16];
#pragma unroll
        for (int mt = 0; mt < 4; ++mt) {
            f32x4 c; c[0] = bv; c[1] = bv; c[2] = bv; c[3] = bv;
            acc[mt][nt] = c;
        }
    }

    // ---- layer-2 GEMM: 4 K-chunks of 32 ----
    for (int c = 0; c < 4; ++c) {
        if (c) __syncthreads();
#pragma unroll
        for (int kk = 0; kk < 32; ++kk) {
            const int k = c * 32 + kk;
            const float pre = fmaf(x0, W0[k], fmaf(x1, W0[128 + k], fmaf(x2, W0[256 + k], b0[k])));
            sbuf[kk * SA + tid] = packsplit(fast_tanh(pre));
        }
        __syncthreads();

        bf16x8 Bhi[4], Blo[4];
#pragma unroll
        for (int nt = 0; nt < 4; ++nt) {
            const int rec = (c * 4 + nt) * 64 + qd * 16 + l16;
            Bhi[nt] = W1fh[rec];
            Blo[nt] = W1fl[rec];
        }
#pragma unroll
        for (int mt = 0; mt < 4; ++mt) {
            unsigned int a[8];
            const int mrow = wv * 64 + mt * 16 + l16;
#pragma unroll
            for (int j = 0; j < 8; ++j) a[j] = sbuf[(qd * 8 + j) * SA + mrow];
            bf16x8 Ahi, Alo;
            unpack8(a, Ahi, Alo);
#pragma unroll
            for (int nt = 0; nt < 4; ++nt) {
                acc[mt][nt] = __builtin_amdgcn_mfma_f32_16x16x32_bf16(Ahi, Bhi[nt], acc[mt][nt], 0, 0, 0);
                acc[mt][nt] = __builtin_amdgcn_mfma_f32_16x16x32_bf16(Ahi, Blo[nt], acc[mt][nt], 0, 0, 0);
                acc[mt][nt] = __builtin_amdgcn_mfma_f32_16x16x32_bf16(Alo, Bhi[nt], acc[mt][nt], 0, 0, 0);
            }
        }
    }

    // ---- expert-A accumulators, init ba ----
    f32x4 acc2[4][2];
#pragma unroll
    for (int nt2 = 0; nt2 < 2; ++nt2) {
        const float bv = ba[(eid << 5) + nt2 * 16 + l16];
#pragma unroll
        for (int mt = 0; mt < 4; ++mt) {
            f32x4 c; c[0] = bv; c[1] = bv; c[2] = bv; c[3] = bv;
            acc2[mt][nt2] = c;
        }
    }

    // ---- expert-A GEMM: h2 = tanh(acc) restaged [d][sample]; 2 K-chunks ----
    const bf16x8* __restrict__ waeh = Wafh + (eid << 8);
    const bf16x8* __restrict__ wael = Wafl + (eid << 8);
    for (int c2 = 0; c2 < 2; ++c2) {
        __syncthreads();
#pragma unroll
        for (int mt = 0; mt < 4; ++mt) {
#pragma unroll
            for (int ntl = 0; ntl < 2; ++ntl) {
#pragma unroll
                for (int r = 0; r < 4; ++r) {
                    const float h2 = fast_tanh(acc[mt][c2 * 2 + ntl][r]);
                    const int dl  = ntl * 16 + l16;
                    const int row = wv * 64 + mt * 16 + qd * 4 + r;
                    sbuf[dl * SA + row] = packsplit(h2);
                }
            }
        }
        __syncthreads();

        bf16x8 B2hi[2], B2lo[2];
#pragma unroll
        for (int nt2 = 0; nt2 < 2; ++nt2) {
            const int rec = (c2 * 2 + nt2) * 64 + qd * 16 + l16;
            B2hi[nt2] = waeh[rec];
            B2lo[nt2] = wael[rec];
        }
#pragma unroll
        for (int mt = 0; mt < 4; ++mt) {
            unsigned int a[8];
            const int mrow = wv * 64 + mt * 16 + l16;
#pragma unroll
            for (int j = 0; j < 8; ++j) a[j] = sbuf[(qd * 8 + j) * SA + mrow];
            bf16x8 Ahi, Alo;
            unpack8(a, Ahi, Alo);
#pragma unroll
            for (int nt2 = 0; nt2 < 2; ++nt2) {
                acc2[mt][nt2] = __builtin_amdgcn_mfma_f32_16x16x32_bf16(Ahi, B2hi[nt2], acc2[mt][nt2], 0, 0, 0);
                acc2[mt][nt2] = __builtin_amdgcn_mfma_f32_16x16x32_bf16(Ahi, B2lo[nt2], acc2[mt][nt2], 0, 0, 0);
                acc2[mt][nt2] = __builtin_amdgcn_mfma_f32_16x16x32_bf16(Alo, B2hi[nt2], acc2[mt][nt2], 0, 0, 0);
            }
        }
    }

    // ---- g = tanh(acc2) staged [sample][h], expert-B per-thread ----
    __syncthreads();
    float* g2 = (float*)sbuf;
#pragma unroll
    for (int mt = 0; mt < 4; ++mt) {
#pragma unroll
        for (int nt2 = 0; nt2 < 2; ++nt2) {
#pragma unroll
            for (int r = 0; r < 4; ++r) {
                const int row = wv * 64 + mt * 16 + qd * 4 + r;
                g2[row * SG + nt2 * 16 + l16] = fast_tanh(acc2[mt][nt2][r]);
            }
        }
    }
    __syncthreads();

    float gv[32];
    {
        const float4* grow = (const float4*)(g2 + tid * SG);
#pragma unroll
        for (int i = 0; i < 8; ++i) {
            float4 v = grow[i];
            gv[4 * i + 0] = v.x; gv[4 * i + 1] = v.y;
            gv[4 * i + 2] = v.z; gv[4 * i + 3] = v.w;
        }
    }

    const float* __restrict__ wbe = Wb + (eid << 6);
    float p0 = bb[2 * eid], p1 = bb[2 * eid + 1];
#pragma unroll
    for (int h = 0; h < 32; ++h) {
        p0 = fmaf(gv[h], wbe[2 * h + 0], p0);
        p1 = fmaf(gv[h], wbe[2 * h + 1], p1);
    }

    const float s = fmaf(p0, p0, fmaf(p1, p1, 1e-6f));
    const float inv = 1.0f / sqrtf(s);
    if (valid) {
        float2 o; o.x = p0 * inv; o.y = p1 * inv;
        ((float2*)out)[idx] = o;
    }
}

extern "C" void kernel_launch(void* const* d_in, const int* in_sizes, int n_in,
                              void* d_out, int out_size, void* d_ws, size_t ws_size,
                              hipStream_t stream) {
    const float* x  = (const float*)d_in[0];
    const int*   n  = (const int*)d_in[1];
    const int*   l  = (const int*)d_in[2];
    const int*   m  = (const int*)d_in[3];
    const float* W0 = (const float*)d_in[4];
    const float* b0 = (const float*)d_in[5];
    const float* W1 = (const float*)d_in[6];
    const float* b1 = (const float*)d_in[7];
    const float* Wa = (const float*)d_in[8];
    const float* ba = (const float*)d_in[9];
    const float* Wb = (const float*)d_in[10];
    const float* bb = (const float*)d_in[11];
    float* out = (float*)d_out;

    const int B = in_sizes[1];   // 262144

    // workspace layout (all segments 16B aligned)
    int*            perm  = (int*)d_ws;                      // B
    int*            eids  = perm + B;                        // B
    int*            bbase = eids + B;                        // HB*NE = 7680
    int*            etot  = bbase + HB * NE;                 // NE*ETS = 480 (pad 512)
    int4*           desc  = (int4*)(etot + 512);             // MAXBLK int4
    unsigned short* W1fh  = (unsigned short*)(desc + MAXBLK);// 8192 u16
    unsigned short* W1fl  = W1fh + 8192;                     // 8192 u16
    unsigned short* Wafh  = W1fl + 8192;                     // 30*2048 u16
    unsigned short* Wafl  = Wafh + NE * 2048;                // 30*2048 u16

    hipMemsetAsync(etot, 0, NE * ETS * sizeof(int), stream);
    hist_pack_kernel<<<HB + 1 + NE, 256, 0, stream>>>(
        n, l, m, eids, etot, bbase, W1, W1fh, W1fl, Wa, Wafh, Wafl, B);
    scatter_kernel<<<HB + 1, 256, 0, stream>>>(eids, etot, bbase, perm, desc, B);
    wfc_kernel<<<MAXBLK, THREADS, 0, stream>>>(
        x, perm, desc, W0, b0,
        (const bf16x8*)W1fh, (const bf16x8*)W1fl, b1,
        (const bf16x8*)Wafh, (const bf16x8*)Wafl, ba, Wb, bb, out);
}